// Round 7
// baseline (1343.793 us; speedup 1.0000x reference)
//
#include <hip/hip_runtime.h>
#include <cstddef>

#define NN 50000
#define NE 800000
#define D 128
#define BN_EPS 1e-5f

typedef __attribute__((ext_vector_type(8))) short bf16x8;
typedef __attribute__((ext_vector_type(4))) float f32x4;

union FragU { int4 i; bf16x8 v; };

__device__ __forceinline__ unsigned short f2bf(float x) {
    unsigned u = __float_as_uint(x);
    return (unsigned short)((u + 0x7fffu + ((u >> 16) & 1u)) >> 16);  // RNE
}
__device__ __forceinline__ float bf2f(unsigned short b) {
    return __uint_as_float(((unsigned)b) << 16);
}
__device__ __forceinline__ unsigned pk2(float a, float b) {
    return (unsigned)f2bf(a) | ((unsigned)f2bf(b) << 16);
}

// mid-layer permutation: pi(16*ct + s) = 32*(ct&3) + 8*(s>>2) + 4*(ct>>2) + (s&3)
__device__ __forceinline__ int pi_perm(int ct, int s) {
    return 32 * (ct & 3) + 8 * (s >> 2) + 4 * (ct >> 2) + (s & 3);
}

// ---------------------------------------------------------------------------
// W prep, plain: fragment-linear bf16 (verified R2/R3)
// ---------------------------------------------------------------------------
__global__ __launch_bounds__(256) void wprep_kernel(
    const float* __restrict__ W, unsigned short* __restrict__ Wt)
{
    const int idx = blockIdx.x * 256 + threadIdx.x;   // [0, 16384)
    const int j  = idx & 7;
    const int l  = (idx >> 3) & 63;
    const int ks = (idx >> 9) & 3;
    const int ct = (idx >> 11) & 7;
    const int n  = 16 * ct + (l & 15);
    const int k  = 32 * ks + ((l >> 4) << 3) + j;
    Wt[idx] = f2bf(W[k * 128 + n]);
}

// W prep with permuted output-column (layer-1): n = pi(16ct + i)
__global__ __launch_bounds__(256) void wprep_pi_kernel(
    const float* __restrict__ W, unsigned short* __restrict__ Wt)
{
    const int idx = blockIdx.x * 256 + threadIdx.x;   // [0, 16384)
    const int j  = idx & 7;
    const int l  = (idx >> 3) & 63;
    const int ks = (idx >> 9) & 3;
    const int ct = (idx >> 11) & 7;
    const int n  = pi_perm(ct, l & 15);
    const int k  = 32 * ks + ((l >> 4) << 3) + j;
    Wt[idx] = f2bf(W[k * 128 + n]);
}

// permuted layer-1 bias: bp[16ct+s] = b[pi(16ct+s)]
__global__ void bprep_kernel(const float* __restrict__ b, float* __restrict__ bp)
{
    const int p = threadIdx.x;   // 128 threads
    bp[p] = b[pi_perm(p >> 4, p & 15)];
}

// ---------------------------------------------------------------------------
// Shuffle-free MFMA 2-layer MLP (pi-permuted, both GEMMs swapped) — R5 inner
// structure. MODE 0 NOW WALKS EDGES IN DST-SORTED (CSR) ORDER: the 16 rows of
// a tile are consecutive sorted positions -> same/neighboring dst node -> the
// h[dst] gather becomes an L1 broadcast. sd[j] = {src,dst} pre-gathered in
// sorted order (sequential loads). Output stored to the edge's original row.
// MODE 1: X = h[row]+agg[row], sequential.
// ---------------------------------------------------------------------------
template<int MODE>
__global__ __launch_bounds__(512, 2) void mlp_mfma_kernel(
    const float* __restrict__ h, const float* __restrict__ e_or_agg,
    const int* __restrict__ csr, const int2* __restrict__ sd,
    const unsigned short* __restrict__ Wt1, const float* __restrict__ b1p,
    const unsigned short* __restrict__ Wt2, const float* __restrict__ b2,
    float* __restrict__ x2out)
{
    __shared__ __align__(16) unsigned short W1L[16384];   // 32 KB
    __shared__ __align__(16) unsigned short W2L[16384];   // 32 KB

    const int tid  = threadIdx.x;
    const int lane = tid & 63;
    const int w    = tid >> 6;        // 0..7
    const int g    = lane >> 4;       // 0..3
    const int m    = lane & 15;
    const long ROWS = (MODE == 0) ? NE : NN;
    const long blockBase = (long)blockIdx.x * 512;

    // ---- stage W1+W2 fragments to LDS (one barrier per block) ----
    {
        int4* d1 = (int4*)W1L;  const int4* s1 = (const int4*)Wt1;
        int4* d2 = (int4*)W2L;  const int4* s2 = (const int4*)Wt2;
#pragma unroll
        for (int i = 0; i < 4; ++i) {
            d1[tid + 512 * i] = s1[tid + 512 * i];
            d2[tid + 512 * i] = s2[tid + 512 * i];
        }
    }
    __syncthreads();
    const bf16x8* W1f = (const bf16x8*)W1L;
    const bf16x8* W2f = (const bf16x8*)W2L;

#pragma unroll 1
    for (int t = 0; t < 4; ++t) {
        const long rowg = blockBase + 64 * w + 16 * t + m;  // sorted position
        const long rowc = (rowg < ROWS) ? rowg : (ROWS - 1);

        long orow_idx;          // output row (original edge id / node id)
        const float *pa, *pb, *pc = nullptr;
        if (MODE == 0) {
            const int  eidx = csr[rowc];
            const int2 sdv  = sd[rowc];
            orow_idx = eidx;
            pa = e_or_agg + (size_t)eidx * D;
            pb = h + (size_t)sdv.x * D;
            pc = h + (size_t)sdv.y * D;
        } else {
            orow_idx = rowc;
            pa = h + (size_t)rowc * D;
            pb = e_or_agg + (size_t)rowc * D;
        }

        // ---- X B-fragments direct from global, split hi/lo ----
        FragU xh[4], xl[4];
#pragma unroll
        for (int ks = 0; ks < 4; ++ks) {
            const int c = 32 * ks + 8 * g;
            const float4 aa = *(const float4*)(pa + c);
            const float4 ab = *(const float4*)(pa + c + 4);
            const float4 ba = *(const float4*)(pb + c);
            const float4 bb = *(const float4*)(pb + c + 4);
            float xs[8];
            xs[0] = aa.x + ba.x; xs[1] = aa.y + ba.y;
            xs[2] = aa.z + ba.z; xs[3] = aa.w + ba.w;
            xs[4] = ab.x + bb.x; xs[5] = ab.y + bb.y;
            xs[6] = ab.z + bb.z; xs[7] = ab.w + bb.w;
            if (MODE == 0) {
                const float4 ca = *(const float4*)(pc + c);
                const float4 cb = *(const float4*)(pc + c + 4);
                xs[0] += ca.x; xs[1] += ca.y; xs[2] += ca.z; xs[3] += ca.w;
                xs[4] += cb.x; xs[5] += cb.y; xs[6] += cb.z; xs[7] += cb.w;
            }
            const unsigned h0 = pk2(xs[0], xs[1]), h1 = pk2(xs[2], xs[3]);
            const unsigned h2 = pk2(xs[4], xs[5]), h3 = pk2(xs[6], xs[7]);
            xh[ks].i = make_int4(h0, h1, h2, h3);
            xl[ks].i = make_int4(
                pk2(xs[0] - bf2f((unsigned short)h0),
                    xs[1] - bf2f((unsigned short)(h0 >> 16))),
                pk2(xs[2] - bf2f((unsigned short)h1),
                    xs[3] - bf2f((unsigned short)(h1 >> 16))),
                pk2(xs[4] - bf2f((unsigned short)h2),
                    xs[5] - bf2f((unsigned short)(h2 >> 16))),
                pk2(xs[6] - bf2f((unsigned short)h3),
                    xs[7] - bf2f((unsigned short)(h3 >> 16))));
        }

        // ---- GEMM1 swapped+permuted: acc[ct][r] = Y[m][pi(16ct+4g+r)] ----
        f32x4 acc[8];
#pragma unroll
        for (int ct = 0; ct < 8; ++ct) acc[ct] = (f32x4){0.f, 0.f, 0.f, 0.f};
#pragma unroll
        for (int ct = 0; ct < 8; ++ct)
#pragma unroll
            for (int ks = 0; ks < 4; ++ks) {
                const bf16x8 wf = W1f[(ct * 4 + ks) * 64 + lane];
                acc[ct] = __builtin_amdgcn_mfma_f32_16x16x32_bf16(wf, xh[ks].v, acc[ct], 0, 0, 0);
                acc[ct] = __builtin_amdgcn_mfma_f32_16x16x32_bf16(wf, xl[ks].v, acc[ct], 0, 0, 0);
            }

        // ---- bias+relu, pack GEMM2 B-frags in-lane ----
        FragU yh[4], yl[4];
#pragma unroll
        for (int ks2 = 0; ks2 < 4; ++ks2) {
            const float4 bva = *(const float4*)(b1p + 16 * ks2 + 4 * g);
            const float4 bvb = *(const float4*)(b1p + 16 * (ks2 + 4) + 4 * g);
            const float y0 = fmaxf(acc[ks2][0] + bva.x, 0.f);
            const float y1 = fmaxf(acc[ks2][1] + bva.y, 0.f);
            const float y2 = fmaxf(acc[ks2][2] + bva.z, 0.f);
            const float y3 = fmaxf(acc[ks2][3] + bva.w, 0.f);
            const float y4 = fmaxf(acc[ks2 + 4][0] + bvb.x, 0.f);
            const float y5 = fmaxf(acc[ks2 + 4][1] + bvb.y, 0.f);
            const float y6 = fmaxf(acc[ks2 + 4][2] + bvb.z, 0.f);
            const float y7 = fmaxf(acc[ks2 + 4][3] + bvb.w, 0.f);
            const unsigned u0 = pk2(y0, y1), u1 = pk2(y2, y3);
            const unsigned u2 = pk2(y4, y5), u3 = pk2(y6, y7);
            yh[ks2].i = make_int4(u0, u1, u2, u3);
            yl[ks2].i = make_int4(
                pk2(y0 - bf2f((unsigned short)u0), y1 - bf2f((unsigned short)(u0 >> 16))),
                pk2(y2 - bf2f((unsigned short)u1), y3 - bf2f((unsigned short)(u1 >> 16))),
                pk2(y4 - bf2f((unsigned short)u2), y5 - bf2f((unsigned short)(u2 >> 16))),
                pk2(y6 - bf2f((unsigned short)u3), y7 - bf2f((unsigned short)(u3 >> 16))));
        }

        // ---- GEMM2 swapped: acc2[ct2][r] = Z[m][16ct2+4g+r] ----
        f32x4 acc2[8];
#pragma unroll
        for (int ct2 = 0; ct2 < 8; ++ct2) acc2[ct2] = (f32x4){0.f, 0.f, 0.f, 0.f};
#pragma unroll
        for (int ct2 = 0; ct2 < 8; ++ct2)
#pragma unroll
            for (int ks2 = 0; ks2 < 4; ++ks2) {
                const bf16x8 wf = W2f[(ct2 * 4 + ks2) * 64 + lane];
                acc2[ct2] = __builtin_amdgcn_mfma_f32_16x16x32_bf16(wf, yh[ks2].v, acc2[ct2], 0, 0, 0);
                acc2[ct2] = __builtin_amdgcn_mfma_f32_16x16x32_bf16(wf, yl[ks2].v, acc2[ct2], 0, 0, 0);
            }

        // ---- bias + row-major float4 store to original row ----
        if (rowg < ROWS) {
            float* orow = x2out + (size_t)orow_idx * D;
#pragma unroll
            for (int ct2 = 0; ct2 < 8; ++ct2) {
                const float4 bv = *(const float4*)(b2 + 16 * ct2 + 4 * g);
                float4 v;
                v.x = acc2[ct2][0] + bv.x;
                v.y = acc2[ct2][1] + bv.y;
                v.z = acc2[ct2][2] + bv.z;
                v.w = acc2[ct2][3] + bv.w;
                *(float4*)(orow + 16 * ct2 + 4 * g) = v;
            }
        }
    }
}

// ---------------------------------------------------------------------------
// Streaming per-column sum/sumsq over a row-major [rows x 128] f32 matrix.
// ---------------------------------------------------------------------------
__global__ __launch_bounds__(256) void col_stats_kernel(
    const float* __restrict__ x, long rows, float* __restrict__ stats)
{
    __shared__ float red[2048];
    const int tid = threadIdx.x;
    const int cg  = tid & 31;
    const int rg  = tid >> 5;
    const int c0  = cg * 4;

    float4 s = make_float4(0.f, 0.f, 0.f, 0.f);
    float4 q = make_float4(0.f, 0.f, 0.f, 0.f);
    for (long r = (long)blockIdx.x * 8 + rg; r < rows; r += (long)gridDim.x * 8) {
        const float4 v = *(const float4*)(x + r * D + c0);
        s.x += v.x; s.y += v.y; s.z += v.z; s.w += v.w;
        q.x += v.x * v.x; q.y += v.y * v.y;
        q.z += v.z * v.z; q.w += v.w * v.w;
    }
    *(float4*)&red[rg * 128 + c0]        = s;
    *(float4*)&red[1024 + rg * 128 + c0] = q;
    __syncthreads();
    if (tid < 128) {
        float ss = 0.f, qq = 0.f;
#pragma unroll
        for (int i = 0; i < 8; ++i) {
            ss += red[i * 128 + tid];
            qq += red[1024 + i * 128 + tid];
        }
        unsafeAtomicAdd(&stats[tid], ss);
        unsafeAtomicAdd(&stats[128 + tid], qq);
    }
}

// stats layout: [0:128) sum, [128:256) sumsq, [256:384) scale, [384:512) shift
__global__ void bn_finalize_kernel(float* __restrict__ stats,
                                   const float* __restrict__ gamma,
                                   const float* __restrict__ beta,
                                   float inv_count)
{
    const int c = threadIdx.x;
    if (c < D) {
        const float mu  = stats[c] * inv_count;
        const float var = stats[128 + c] * inv_count - mu * mu;
        const float sc  = rsqrtf(var + BN_EPS) * gamma[c];
        stats[256 + c] = sc;
        stats[384 + c] = beta[c] - mu * sc;
    }
}

// ---- CSR build ----
__global__ __launch_bounds__(256) void hist_kernel(
    const int* __restrict__ dst, int* __restrict__ cnt)
{
    const int i = blockIdx.x * 256 + threadIdx.x;
    if (i < NE) atomicAdd(&cnt[dst[i]], 1);
}

__global__ __launch_bounds__(1024) void scan_kernel(
    const int* __restrict__ cnt, int* __restrict__ off)
{
    __shared__ int part[1024];
    const int t = threadIdx.x;
    const int SEG = (NN + 1023) / 1024;
    const int base = t * SEG;

    int s = 0;
    for (int i = 0; i < SEG; ++i) {
        const int idx = base + i;
        if (idx < NN) s += cnt[idx];
    }
    part[t] = s;
    __syncthreads();
    for (int d = 1; d < 1024; d <<= 1) {
        int v = (t >= d) ? part[t - d] : 0;
        __syncthreads();
        part[t] += v;
        __syncthreads();
    }
    int run = (t > 0) ? part[t - 1] : 0;
    for (int i = 0; i < SEG; ++i) {
        const int idx = base + i;
        if (idx < NN) { off[idx] = run; run += cnt[idx]; }
    }
    if (t == 1023) off[NN] = part[1023];
}

// scatter edge ids into CSR slots; also materialize sorted {src,dst} pairs
__global__ __launch_bounds__(256) void csr_scatter_kernel(
    const int* __restrict__ src, const int* __restrict__ dst,
    const int* __restrict__ off, int* __restrict__ cnt,
    int* __restrict__ csr, int2* __restrict__ sd)
{
    const int i = blockIdx.x * 256 + threadIdx.x;
    if (i < NE) {
        const int d = dst[i];
        const int p = atomicSub(&cnt[d], 1) - 1;
        const int j = off[d] + p;
        csr[j] = i;
        sd[j] = make_int2(src[i], d);
    }
}

// ---------------------------------------------------------------------------
// Fused BN-apply + residual + segment-sum gather (one wave per node),
// 2-edge manual ILP to overlap random-row load latency.
// ---------------------------------------------------------------------------
__global__ __launch_bounds__(256) void apply_gather_kernel(
    const float* __restrict__ e, const float* __restrict__ stats,
    const int* __restrict__ off, const int* __restrict__ csr,
    float* __restrict__ eout, float* __restrict__ agg)
{
    const int node = blockIdx.x * 4 + (threadIdx.x >> 6);
    const int lane = threadIdx.x & 63;
    const int c0   = lane * 2;
    if (node >= NN) return;

    const float2 sc = *(const float2*)(stats + 256 + c0);
    const float2 sh = *(const float2*)(stats + 384 + c0);
    float2 acc = make_float2(0.f, 0.f);
    const int jb = off[node], je = off[node + 1];
    int j = jb;
    for (; j + 2 <= je; j += 2) {
        const int e0 = csr[j];
        const int e1 = csr[j + 1];
        const size_t b0 = (size_t)e0 * D + c0;
        const size_t b1 = (size_t)e1 * D + c0;
        const float2 x0  = *(const float2*)(eout + b0);
        const float2 ev0 = *(const float2*)(e + b0);
        const float2 x1  = *(const float2*)(eout + b1);
        const float2 ev1 = *(const float2*)(e + b1);
        float2 v0, v1;
        v0.x = fmaf(x0.x, sc.x, sh.x) + ev0.x;
        v0.y = fmaf(x0.y, sc.y, sh.y) + ev0.y;
        v1.x = fmaf(x1.x, sc.x, sh.x) + ev1.x;
        v1.y = fmaf(x1.y, sc.y, sh.y) + ev1.y;
        *(float2*)(eout + b0) = v0;
        *(float2*)(eout + b1) = v1;
        acc.x += v0.x + v1.x;
        acc.y += v0.y + v1.y;
    }
    if (j < je) {
        const int e0 = csr[j];
        const size_t b0 = (size_t)e0 * D + c0;
        const float2 x0  = *(const float2*)(eout + b0);
        const float2 ev0 = *(const float2*)(e + b0);
        float2 v0;
        v0.x = fmaf(x0.x, sc.x, sh.x) + ev0.x;
        v0.y = fmaf(x0.y, sc.y, sh.y) + ev0.y;
        *(float2*)(eout + b0) = v0;
        acc.x += v0.x;
        acc.y += v0.y;
    }
    *(float2*)(agg + (size_t)node * D + c0) = acc;
}

// h_new = y2*scale + shift + h (in-place over y2 in d_out)
__global__ __launch_bounds__(256) void node_apply_kernel(
    const float* __restrict__ h, const float* __restrict__ stats,
    float* __restrict__ hout)
{
    const int gid = blockIdx.x * 256 + threadIdx.x;
    const int c0  = (gid & 31) * 4;
    const size_t base = (size_t)(gid >> 5) * D + c0;

    const float4 sc = *(const float4*)(stats + 256 + c0);
    const float4 sh = *(const float4*)(stats + 384 + c0);
    const float4 x  = *(const float4*)(hout + base);
    const float4 hv = *(const float4*)(h + base);
    float4 v;
    v.x = fmaf(x.x, sc.x, sh.x) + hv.x;
    v.y = fmaf(x.y, sc.y, sh.y) + hv.y;
    v.z = fmaf(x.z, sc.z, sh.z) + hv.z;
    v.w = fmaf(x.w, sc.w, sh.w) + hv.w;
    *(float4*)(hout + base) = v;
}

extern "C" void kernel_launch(void* const* d_in, const int* in_sizes, int n_in,
                              void* d_out, int out_size, void* d_ws, size_t ws_size,
                              hipStream_t stream)
{
    const float* h   = (const float*)d_in[0];
    const float* e   = (const float*)d_in[1];
    const int*   src = (const int*)d_in[2];
    const int*   dst = (const int*)d_in[3];
    const float* Wa1 = (const float*)d_in[4];
    const float* ba1 = (const float*)d_in[5];
    const float* Wa2 = (const float*)d_in[6];
    const float* ba2 = (const float*)d_in[7];
    const float* Wb1 = (const float*)d_in[8];
    const float* bb1 = (const float*)d_in[9];
    const float* Wb2 = (const float*)d_in[10];
    const float* bb2 = (const float*)d_in[11];
    const float* ga  = (const float*)d_in[12];
    const float* bea = (const float*)d_in[13];
    const float* gb  = (const float*)d_in[14];
    const float* beb = (const float*)d_in[15];

    float* out  = (float*)d_out;
    float* hnew = out;                      // NN*D (y2 scratch, then h_new)
    float* enew = out + (size_t)NN * D;     // NE*D (x2 scratch, then e_new)

    // ws layout (float units):
    //   estats[512] | nstats[512] | icnt[NN] | ioff[NN+1] | pad3 |
    //   b1pe[128] | b1pn[128] | wtb1/wtb2/wta1/wta2 (4 x 16384 ushort) |
    //   csr[NE ints] | sd[NE int2] | agg[NN*D]
    float* ws     = (float*)d_ws;
    float* estats = ws;
    float* nstats = ws + 512;
    int*   icnt   = (int*)(ws + 1024);
    int*   ioff   = icnt + NN;
    float* b1pe   = (float*)(ioff + NN + 1 + 3);       // 16B aligned
    float* b1pn   = b1pe + 128;
    unsigned short* wtb1 = (unsigned short*)(b1pn + 128);
    unsigned short* wtb2 = wtb1 + 16384;
    unsigned short* wta1 = wtb2 + 16384;
    unsigned short* wta2 = wta1 + 16384;
    int*   icsr = (int*)(wta2 + 16384);
    int2*  isd  = (int2*)(icsr + NE);
    float* agg  = (float*)(isd + NE);

    // zero BN stats + histogram counters
    hipMemsetAsync(d_ws, 0, (size_t)(1024 + NN) * sizeof(float), stream);

    // ---- weight/bias prep ----
    wprep_pi_kernel<<<64, 256, 0, stream>>>(Wb1, wtb1);
    wprep_kernel<<<64, 256, 0, stream>>>(Wb2, wtb2);
    wprep_pi_kernel<<<64, 256, 0, stream>>>(Wa1, wta1);
    wprep_kernel<<<64, 256, 0, stream>>>(Wa2, wta2);
    bprep_kernel<<<1, 128, 0, stream>>>(bb1, b1pe);
    bprep_kernel<<<1, 128, 0, stream>>>(ba1, b1pn);

    // ---- CSR build (+ sorted {src,dst} pairs) ----
    hist_kernel<<<(NE + 255) / 256, 256, 0, stream>>>(dst, icnt);
    scan_kernel<<<1, 1024, 0, stream>>>(icnt, ioff);
    csr_scatter_kernel<<<(NE + 255) / 256, 256, 0, stream>>>(src, dst, ioff,
                                                             icnt, icsr, isd);

    // ---- bond (edge) path: MLP in dst-sorted order ----
    mlp_mfma_kernel<0><<<(NE + 511) / 512, 512, 0, stream>>>(
        h, e, icsr, isd, wtb1, b1pe, wtb2, bb2, enew /*x2*/);
    col_stats_kernel<<<2048, 256, 0, stream>>>(enew, (long)NE, estats);
    bn_finalize_kernel<<<1, 128, 0, stream>>>(estats, gb, beb, 1.0f / NE);
    apply_gather_kernel<<<(NN + 3) / 4, 256, 0, stream>>>(e, estats, ioff, icsr,
                                                          enew, agg);

    // ---- atom (node) path ----
    mlp_mfma_kernel<1><<<(NN + 511) / 512, 512, 0, stream>>>(
        h, agg, nullptr, nullptr, wta1, b1pn, wta2, ba2, hnew /*y2*/);
    col_stats_kernel<<<256, 256, 0, stream>>>(hnew, (long)NN, nstats);
    bn_finalize_kernel<<<1, 128, 0, stream>>>(nstats, ga, bea, 1.0f / NN);
    node_apply_kernel<<<(NN * 32) / 256, 256, 0, stream>>>(h, nstats, hnew);
}

// Round 12
// 802.888 us; speedup vs baseline: 1.6737x; 1.6737x over previous
//
#include <hip/hip_runtime.h>
#include <hip/hip_fp16.h>
#include <cstddef>

#define NN 50000
#define NE 800000
#define D 128
#define BN_EPS 1e-5f

typedef __attribute__((ext_vector_type(8))) short bf16x8;
typedef __attribute__((ext_vector_type(4))) float f32x4;
typedef __attribute__((ext_vector_type(4))) unsigned short us4;

__device__ __forceinline__ unsigned short f2bf(float x) {
    unsigned u = __float_as_uint(x);
    return (unsigned short)((u + 0x7fffu + ((u >> 16) & 1u)) >> 16);  // RNE
}
__device__ __forceinline__ float bf2f(unsigned short b) {
    return __uint_as_float(((unsigned)b) << 16);
}

// ---------------------------------------------------------------------------
// W prep: W[k][n] f32 -> fragment-linear bf16 Wt (verified R2: B-operand frag)
// Wt[((ct*4+ks)*64 + l)*8 + j] = bf16( W[(32ks + (l>>4)*8 + j)*128 + 16ct + (l&15)] )
// ---------------------------------------------------------------------------
__global__ __launch_bounds__(256) void wprep_kernel(
    const float* __restrict__ W, unsigned short* __restrict__ Wt)
{
    const int idx = blockIdx.x * 256 + threadIdx.x;   // [0, 16384)
    const int j  = idx & 7;
    const int l  = (idx >> 3) & 63;
    const int ks = (idx >> 9) & 3;
    const int ct = (idx >> 11) & 7;
    const int n  = 16 * ct + (l & 15);
    const int k  = 32 * ks + ((l >> 4) << 3) + j;
    Wt[idx] = f2bf(W[k * 128 + n]);
}

// ---------------------------------------------------------------------------
// R2-proven MFMA 2-layer MLP (384 us @ edge): 64-row tile, split-bf16 X in
// XOR-swizzled LDS, W frags in VGPRs, OUTB f32 transpose buffer, in-kernel
// BN stats. HALFX=1 stores x2 as fp16 (half write traffic); HALFX=0 stores
// f32 (exact R2 behavior).
// MODE 0 (edge): X = e+h[src]+h[dst]. MODE 1 (node): X = h+agg (guarded).
// ---------------------------------------------------------------------------
template<int MODE, int HALFX>
__global__ __launch_bounds__(256, 2) void mlp_mfma_kernel(
    const float* __restrict__ h, const float* __restrict__ e_or_agg,
    const int* __restrict__ src, const int* __restrict__ dst,
    const unsigned short* __restrict__ Wt1, const float* __restrict__ b1,
    const unsigned short* __restrict__ Wt2, const float* __restrict__ b2,
    void* __restrict__ x2out_v, float* __restrict__ stats)
{
    __shared__ __align__(16) unsigned short Xh[8192];   // 64 x 128 bf16 (swizzled)
    __shared__ __align__(16) unsigned short Xl[8192];
    __shared__ __align__(16) float OUTB[64 * 132];      // f32 transpose buffer

    const int tid  = threadIdx.x;
    const int lane = tid & 63;
    const int w    = tid >> 6;        // wave id 0..3 -> rows 16w..16w+15
    const int cg   = tid & 31;
    const int rg   = tid >> 5;
    const int c0   = cg * 4;
    const long r0  = (long)blockIdx.x * 64;

    // ---- W1 fragments -> VGPRs ----
    const bf16x8* Wg1 = (const bf16x8*)Wt1;
    bf16x8 wf[8][4];
#pragma unroll
    for (int ct = 0; ct < 8; ++ct)
#pragma unroll
        for (int ks = 0; ks < 4; ++ks)
            wf[ct][ks] = Wg1[(ct * 4 + ks) * 64 + lane];

    // ---- stage X as bf16 hi/lo into swizzled LDS ----
#pragma unroll
    for (int p = 0; p < 8; ++p) {
        const int  row  = p * 8 + rg;
        const long grow = r0 + row;
        float4 v = make_float4(0.f, 0.f, 0.f, 0.f);
        if (MODE == 0) {
            const int sN = src[grow];
            const int dN = dst[grow];
            const float4 ev = *(const float4*)(e_or_agg + (size_t)grow * D + c0);
            const float4 hs = *(const float4*)(h + (size_t)sN * D + c0);
            const float4 hd = *(const float4*)(h + (size_t)dN * D + c0);
            v.x = ev.x + hs.x + hd.x; v.y = ev.y + hs.y + hd.y;
            v.z = ev.z + hs.z + hd.z; v.w = ev.w + hs.w + hd.w;
        } else {
            if (grow < NN) {
                const float4 hv = *(const float4*)(h + (size_t)grow * D + c0);
                const float4 av = *(const float4*)(e_or_agg + (size_t)grow * D + c0);
                v.x = hv.x + av.x; v.y = hv.y + av.y;
                v.z = hv.z + av.z; v.w = hv.w + av.w;
            }
        }
        us4 hi, lo;
        hi.x = f2bf(v.x); lo.x = f2bf(v.x - bf2f(hi.x));
        hi.y = f2bf(v.y); lo.y = f2bf(v.y - bf2f(hi.y));
        hi.z = f2bf(v.z); lo.z = f2bf(v.z - bf2f(hi.z));
        hi.w = f2bf(v.w); lo.w = f2bf(v.w - bf2f(hi.w));
        const int addr = row * 128 + (((c0 >> 3) ^ (row & 7)) << 3) + (c0 & 7);
        *(us4*)&Xh[addr] = hi;
        *(us4*)&Xl[addr] = lo;
    }
    __syncthreads();

    // ---- GEMM1 ----
    const int arow = 16 * w + (lane & 15);
    bf16x8 ah[4], al[4];
#pragma unroll
    for (int ks = 0; ks < 4; ++ks) {
        const int col0  = 32 * ks + ((lane >> 4) << 3);
        const int aaddr = arow * 128 + (((col0 >> 3) ^ (arow & 7)) << 3);
        ah[ks] = *(const bf16x8*)&Xh[aaddr];
        al[ks] = *(const bf16x8*)&Xl[aaddr];
    }
    f32x4 acc[8];
#pragma unroll
    for (int ct = 0; ct < 8; ++ct) acc[ct] = (f32x4){0.f, 0.f, 0.f, 0.f};
#pragma unroll
    for (int ct = 0; ct < 8; ++ct)
#pragma unroll
        for (int ks = 0; ks < 4; ++ks) {
            acc[ct] = __builtin_amdgcn_mfma_f32_16x16x32_bf16(ah[ks], wf[ct][ks], acc[ct], 0, 0, 0);
            acc[ct] = __builtin_amdgcn_mfma_f32_16x16x32_bf16(al[ks], wf[ct][ks], acc[ct], 0, 0, 0);
        }

    // ---- issue W2 loads (overwrite wf) ----
    const bf16x8* Wg2 = (const bf16x8*)Wt2;
#pragma unroll
    for (int ct = 0; ct < 8; ++ct)
#pragma unroll
        for (int ks = 0; ks < 4; ++ks)
            wf[ct][ks] = Wg2[(ct * 4 + ks) * 64 + lane];

    // ---- epilogue1: bias + relu -> f32 transpose buffer ----
#pragma unroll
    for (int ct = 0; ct < 8; ++ct) {
        const float b1c = b1[16 * ct + (lane & 15)];
#pragma unroll
        for (int r = 0; r < 4; ++r) {
            const int row = 16 * w + ((lane >> 4) << 2) + r;
            OUTB[row * 132 + 16 * ct + (lane & 15)] = fmaxf(acc[ct][r] + b1c, 0.f);
        }
    }
    __syncthreads();

    // ---- restage Y as bf16 hi/lo ----
#pragma unroll
    for (int p = 0; p < 8; ++p) {
        const int row = p * 8 + rg;
        const float4 v = *(const float4*)&OUTB[row * 132 + c0];
        us4 hi, lo;
        hi.x = f2bf(v.x); lo.x = f2bf(v.x - bf2f(hi.x));
        hi.y = f2bf(v.y); lo.y = f2bf(v.y - bf2f(hi.y));
        hi.z = f2bf(v.z); lo.z = f2bf(v.z - bf2f(hi.z));
        hi.w = f2bf(v.w); lo.w = f2bf(v.w - bf2f(hi.w));
        const int addr = row * 128 + (((c0 >> 3) ^ (row & 7)) << 3) + (c0 & 7);
        *(us4*)&Xh[addr] = hi;
        *(us4*)&Xl[addr] = lo;
    }
    __syncthreads();

    // ---- GEMM2 ----
#pragma unroll
    for (int ks = 0; ks < 4; ++ks) {
        const int col0  = 32 * ks + ((lane >> 4) << 3);
        const int aaddr = arow * 128 + (((col0 >> 3) ^ (arow & 7)) << 3);
        ah[ks] = *(const bf16x8*)&Xh[aaddr];
        al[ks] = *(const bf16x8*)&Xl[aaddr];
    }
    f32x4 a2[8];
#pragma unroll
    for (int ct = 0; ct < 8; ++ct) a2[ct] = (f32x4){0.f, 0.f, 0.f, 0.f};
#pragma unroll
    for (int ct = 0; ct < 8; ++ct)
#pragma unroll
        for (int ks = 0; ks < 4; ++ks) {
            a2[ct] = __builtin_amdgcn_mfma_f32_16x16x32_bf16(ah[ks], wf[ct][ks], a2[ct], 0, 0, 0);
            a2[ct] = __builtin_amdgcn_mfma_f32_16x16x32_bf16(al[ks], wf[ct][ks], a2[ct], 0, 0, 0);
        }

    // ---- epilogue2: bias -> f32 transpose buffer ----
#pragma unroll
    for (int ct = 0; ct < 8; ++ct) {
        const float b2c = b2[16 * ct + (lane & 15)];
#pragma unroll
        for (int r = 0; r < 4; ++r) {
            const int row = 16 * w + ((lane >> 4) << 2) + r;
            OUTB[row * 132 + 16 * ct + (lane & 15)] = a2[ct][r] + b2c;
        }
    }
    __syncthreads();

    // ---- coalesced store (fp16 or f32) + BN stats partials ----
    float ts[4] = {0.f, 0.f, 0.f, 0.f};
    float tq[4] = {0.f, 0.f, 0.f, 0.f};
#pragma unroll
    for (int p = 0; p < 8; ++p) {
        const int  row  = p * 8 + rg;
        const long grow = r0 + row;
        if (MODE == 1 && grow >= NN) continue;
        const float4 v = *(const float4*)&OUTB[row * 132 + c0];
        if (HALFX) {
            __half* xp = (__half*)x2out_v + (size_t)grow * D + c0;
            *(__half2*)(xp)     = __floats2half2_rn(v.x, v.y);
            *(__half2*)(xp + 2) = __floats2half2_rn(v.z, v.w);
        } else {
            *(float4*)((float*)x2out_v + (size_t)grow * D + c0) = v;
        }
        ts[0] += v.x; ts[1] += v.y; ts[2] += v.z; ts[3] += v.w;
        tq[0] += v.x * v.x; tq[1] += v.y * v.y;
        tq[2] += v.z * v.z; tq[3] += v.w * v.w;
    }

    float* red = (float*)Xh;   // Xh/Xl fully consumed
    *(float4*)&red[rg * 128 + c0]        = make_float4(ts[0], ts[1], ts[2], ts[3]);
    *(float4*)&red[2048 + rg * 128 + c0] = make_float4(tq[0], tq[1], tq[2], tq[3]);
    __syncthreads();
    if (tid < 128) {
        float s = 0.f, q = 0.f;
#pragma unroll
        for (int g = 0; g < 8; ++g) {
            s += red[g * 128 + tid];
            q += red[2048 + g * 128 + tid];
        }
        unsafeAtomicAdd(&stats[tid], s);
        unsafeAtomicAdd(&stats[128 + tid], q);
    }
}

// stats layout: [0:128) sum, [128:256) sumsq, [256:384) scale, [384:512) shift
__global__ void bn_finalize_kernel(float* __restrict__ stats,
                                   const float* __restrict__ gamma,
                                   const float* __restrict__ beta,
                                   float inv_count)
{
    const int c = threadIdx.x;
    if (c < D) {
        const float mu  = stats[c] * inv_count;
        const float var = stats[128 + c] * inv_count - mu * mu;
        const float sc  = rsqrtf(var + BN_EPS) * gamma[c];
        stats[256 + c] = sc;
        stats[384 + c] = beta[c] - mu * sc;
    }
}

// ---- CSR build ----
__global__ __launch_bounds__(256) void hist_kernel(
    const int* __restrict__ dst, int* __restrict__ cnt)
{
    const int i = blockIdx.x * 256 + threadIdx.x;
    if (i < NE) atomicAdd(&cnt[dst[i]], 1);
}

__global__ __launch_bounds__(1024) void scan_kernel(
    const int* __restrict__ cnt, int* __restrict__ off)
{
    __shared__ int part[1024];
    const int t = threadIdx.x;
    const int SEG = (NN + 1023) / 1024;
    const int base = t * SEG;

    int s = 0;
    for (int i = 0; i < SEG; ++i) {
        const int idx = base + i;
        if (idx < NN) s += cnt[idx];
    }
    part[t] = s;
    __syncthreads();
    for (int d = 1; d < 1024; d <<= 1) {
        int v = (t >= d) ? part[t - d] : 0;
        __syncthreads();
        part[t] += v;
        __syncthreads();
    }
    int run = (t > 0) ? part[t - 1] : 0;
    for (int i = 0; i < SEG; ++i) {
        const int idx = base + i;
        if (idx < NN) { off[idx] = run; run += cnt[idx]; }
    }
    if (t == 1023) off[NN] = part[1023];
}

__global__ __launch_bounds__(256) void csr_scatter_kernel(
    const int* __restrict__ dst, const int* __restrict__ off,
    int* __restrict__ cnt, int* __restrict__ csr)
{
    const int i = blockIdx.x * 256 + threadIdx.x;
    if (i < NE) {
        const int d = dst[i];
        const int p = atomicSub(&cnt[d], 1) - 1;
        csr[off[d] + p] = i;
    }
}

// ---------------------------------------------------------------------------
// Fused BN-apply + residual + segment-sum gather (one wave per node),
// 2-edge ILP. HALFX=1: x2 read as fp16 from x2src; HALFX=0: x2 read f32
// in-place from eout (exact R2 behavior).
// ---------------------------------------------------------------------------
template<int HALFX>
__global__ __launch_bounds__(256) void apply_gather_kernel(
    const float* __restrict__ e, const float* __restrict__ stats,
    const int* __restrict__ off, const int* __restrict__ csr,
    const void* __restrict__ x2src, float* __restrict__ eout,
    float* __restrict__ agg)
{
    const int node = blockIdx.x * 4 + (threadIdx.x >> 6);
    const int lane = threadIdx.x & 63;
    const int c0   = lane * 2;
    if (node >= NN) return;

    const float2 sc = *(const float2*)(stats + 256 + c0);
    const float2 sh = *(const float2*)(stats + 384 + c0);
    float2 acc = make_float2(0.f, 0.f);
    const int jb = off[node], je = off[node + 1];
    int j = jb;
    for (; j + 2 <= je; j += 2) {
        const int e0 = csr[j];
        const int e1 = csr[j + 1];
        const size_t b0 = (size_t)e0 * D + c0;
        const size_t b1 = (size_t)e1 * D + c0;
        float2 x0, x1;
        if (HALFX) {
            x0 = __half22float2(*(const __half2*)((const __half*)x2src + b0));
            x1 = __half22float2(*(const __half2*)((const __half*)x2src + b1));
        } else {
            x0 = *(const float2*)(eout + b0);
            x1 = *(const float2*)(eout + b1);
        }
        const float2 ev0 = *(const float2*)(e + b0);
        const float2 ev1 = *(const float2*)(e + b1);
        float2 v0, v1;
        v0.x = fmaf(x0.x, sc.x, sh.x) + ev0.x;
        v0.y = fmaf(x0.y, sc.y, sh.y) + ev0.y;
        v1.x = fmaf(x1.x, sc.x, sh.x) + ev1.x;
        v1.y = fmaf(x1.y, sc.y, sh.y) + ev1.y;
        *(float2*)(eout + b0) = v0;
        *(float2*)(eout + b1) = v1;
        acc.x += v0.x + v1.x;
        acc.y += v0.y + v1.y;
    }
    if (j < je) {
        const int e0 = csr[j];
        const size_t b0 = (size_t)e0 * D + c0;
        float2 x0;
        if (HALFX) {
            x0 = __half22float2(*(const __half2*)((const __half*)x2src + b0));
        } else {
            x0 = *(const float2*)(eout + b0);
        }
        const float2 ev0 = *(const float2*)(e + b0);
        float2 v0;
        v0.x = fmaf(x0.x, sc.x, sh.x) + ev0.x;
        v0.y = fmaf(x0.y, sc.y, sh.y) + ev0.y;
        *(float2*)(eout + b0) = v0;
        acc.x += v0.x;
        acc.y += v0.y;
    }
    *(float2*)(agg + (size_t)node * D + c0) = acc;
}

// h_new = y2*scale + shift + h (in-place over y2 in d_out)
__global__ __launch_bounds__(256) void node_apply_kernel(
    const float* __restrict__ h, const float* __restrict__ stats,
    float* __restrict__ hout)
{
    const int gid = blockIdx.x * 256 + threadIdx.x;
    const int c0  = (gid & 31) * 4;
    const size_t base = (size_t)(gid >> 5) * D + c0;

    const float4 sc = *(const float4*)(stats + 256 + c0);
    const float4 sh = *(const float4*)(stats + 384 + c0);
    const float4 x  = *(const float4*)(hout + base);
    const float4 hv = *(const float4*)(h + base);
    float4 v;
    v.x = fmaf(x.x, sc.x, sh.x) + hv.x;
    v.y = fmaf(x.y, sc.y, sh.y) + hv.y;
    v.z = fmaf(x.z, sc.z, sh.z) + hv.z;
    v.w = fmaf(x.w, sc.w, sh.w) + hv.w;
    *(float4*)(hout + base) = v;
}

extern "C" void kernel_launch(void* const* d_in, const int* in_sizes, int n_in,
                              void* d_out, int out_size, void* d_ws, size_t ws_size,
                              hipStream_t stream)
{
    const float* h   = (const float*)d_in[0];
    const float* e   = (const float*)d_in[1];
    const int*   src = (const int*)d_in[2];
    const int*   dst = (const int*)d_in[3];
    const float* Wa1 = (const float*)d_in[4];
    const float* ba1 = (const float*)d_in[5];
    const float* Wa2 = (const float*)d_in[6];
    const float* ba2 = (const float*)d_in[7];
    const float* Wb1 = (const float*)d_in[8];
    const float* bb1 = (const float*)d_in[9];
    const float* Wb2 = (const float*)d_in[10];
    const float* bb2 = (const float*)d_in[11];
    const float* ga  = (const float*)d_in[12];
    const float* bea = (const float*)d_in[13];
    const float* gb  = (const float*)d_in[14];
    const float* beb = (const float*)d_in[15];

    float* out  = (float*)d_out;
    float* hnew = out;                      // NN*D (y2 scratch, then h_new)
    float* enew = out + (size_t)NN * D;     // NE*D (e_new; x2 scratch if f32 path)

    // ws layout (float units):
    //   estats[512] | nstats[512] | icnt[NN] | ioff[NN+1] | pad3 |
    //   wtb1/wtb2/wta1/wta2 (4 x 16384 ushort) | csr[NE ints] | agg[NN*D] |
    //   x2h[NE*D halves]  (only if ws_size permits)
    float* ws     = (float*)d_ws;
    float* estats = ws;
    float* nstats = ws + 512;
    int*   icnt   = (int*)(ws + 1024);
    int*   ioff   = icnt + NN;
    unsigned short* wtb1 = (unsigned short*)(ioff + NN + 1 + 3);  // 16B aligned
    unsigned short* wtb2 = wtb1 + 16384;
    unsigned short* wta1 = wtb2 + 16384;
    unsigned short* wta2 = wta1 + 16384;
    int*    icsr = (int*)(wta2 + 16384);
    float*  agg  = (float*)(icsr + NE);
    __half* x2h  = (__half*)(agg + (size_t)NN * D);
    const size_t need_half = (size_t)((char*)(x2h + (size_t)NE * D) - (char*)d_ws);
    const bool use_half = (ws_size >= need_half);

    // zero BN stats + histogram counters
    hipMemsetAsync(d_ws, 0, (size_t)(1024 + NN) * sizeof(float), stream);

    // ---- weight prep (fragment-linear bf16) ----
    wprep_kernel<<<64, 256, 0, stream>>>(Wb1, wtb1);
    wprep_kernel<<<64, 256, 0, stream>>>(Wb2, wtb2);
    wprep_kernel<<<64, 256, 0, stream>>>(Wa1, wta1);
    wprep_kernel<<<64, 256, 0, stream>>>(Wa2, wta2);

    // ---- CSR build ----
    hist_kernel<<<(NE + 255) / 256, 256, 0, stream>>>(dst, icnt);
    scan_kernel<<<1, 1024, 0, stream>>>(icnt, ioff);
    csr_scatter_kernel<<<(NE + 255) / 256, 256, 0, stream>>>(dst, ioff, icnt, icsr);

    // ---- bond (edge) path ----
    if (use_half) {
        mlp_mfma_kernel<0, 1><<<NE / 64, 256, 0, stream>>>(
            h, e, src, dst, wtb1, bb1, wtb2, bb2, (void*)x2h, estats);
        bn_finalize_kernel<<<1, 128, 0, stream>>>(estats, gb, beb, 1.0f / NE);
        apply_gather_kernel<1><<<(NN + 3) / 4, 256, 0, stream>>>(
            e, estats, ioff, icsr, (const void*)x2h, enew, agg);
    } else {
        mlp_mfma_kernel<0, 0><<<NE / 64, 256, 0, stream>>>(
            h, e, src, dst, wtb1, bb1, wtb2, bb2, (void*)enew, estats);
        bn_finalize_kernel<<<1, 128, 0, stream>>>(estats, gb, beb, 1.0f / NE);
        apply_gather_kernel<0><<<(NN + 3) / 4, 256, 0, stream>>>(
            e, estats, ioff, icsr, nullptr, enew, agg);
    }

    // ---- atom (node) path ----
    mlp_mfma_kernel<1, 0><<<(NN + 63) / 64, 256, 0, stream>>>(
        h, agg, nullptr, nullptr, wta1, ba1, wta2, ba2, (void*)hnew, nstats);
    bn_finalize_kernel<<<1, 128, 0, stream>>>(nstats, ga, bea, 1.0f / NN);
    node_apply_kernel<<<(NN * 32) / 256, 256, 0, stream>>>(h, nstats, hnew);
}